// Round 16
// baseline (170.769 us; speedup 1.0000x reference)
//
#include <hip/hip_runtime.h>
#include <hip/hip_bf16.h>
#include <stdint.h>

#define DM   1024
#define FF   4096
#define NH   16
#define DK   64
#define SEQ  512
#define NTOK 4096

typedef __attribute__((ext_vector_type(8))) unsigned short ushort8;
typedef __attribute__((ext_vector_type(4))) unsigned short ushort4v;
typedef __attribute__((ext_vector_type(8))) short bf16x8;
typedef __attribute__((ext_vector_type(4))) float f32x4;

__device__ __forceinline__ float bf2f(unsigned short u) {
  union { unsigned int i; float f; } v; v.i = ((unsigned int)u) << 16; return v.f;
}
__device__ __forceinline__ unsigned short f2bf(float f) {
  union { float fl; unsigned int i; } v; v.fl = f;
  v.i += 0x7fffu + ((v.i >> 16) & 1u);   // RNE
  return (unsigned short)(v.i >> 16);
}

__device__ __forceinline__ void gload16(const unsigned short* g, unsigned short* l) {
  __builtin_amdgcn_global_load_lds(
      (const __attribute__((address_space(1))) unsigned int*)g,
      (__attribute__((address_space(3))) unsigned int*)l, 16, 0, 0);
}

// ============== mega-prep: src->bf16, 5 weight transposes, bias concat =========
__global__ __launch_bounds__(256)
void prep_kernel(const float* __restrict__ src, unsigned short* __restrict__ srcb,
                 const float* __restrict__ wq, const float* __restrict__ wk,
                 const float* __restrict__ wv, unsigned short* __restrict__ WqkvT,
                 const float* __restrict__ w1, unsigned short* __restrict__ W1T,
                 const float* __restrict__ w2, unsigned short* __restrict__ W2T,
                 const float* __restrict__ bq, const float* __restrict__ bk,
                 const float* __restrict__ bv, float* __restrict__ bqkv) {
  const int z = blockIdx.x;
  const int tid = threadIdx.x;
  if (z < 4096) {                       // src -> bf16 (1024 elems/block)
    const long i = ((long)z * 256 + tid) * 4;
    f32x4 v = *(const f32x4*)(src + i);
    ushort4v o;
#pragma unroll
    for (int j = 0; j < 4; j++) o[j] = f2bf(v[j]);
    *(ushort4v*)(srcb + i) = o;
    return;
  }
  if (z >= 15360) {                     // bias concat
    const int i = (z - 15360) * 256 + tid;
    if (i < 3072)
      bqkv[i] = (i < 1024) ? bq[i] : ((i < 2048) ? bk[i - 1024] : bv[i - 2048]);
    return;
  }
  // 32x32 transpose tile tasks
  const float* in;
  unsigned short* out;
  int ldin, ldout;
  long r0, c0;
  if (z < 7168) {                       // wq/wk/wv: [1024][1024]
    const int w = (z - 4096) >> 10;
    const int t = (z - 4096) & 1023;
    in = (w == 0) ? wq : (w == 1) ? wk : wv;
    out = WqkvT + (long)w * 1024 * 1024;
    ldin = 1024; ldout = 1024;
    r0 = (long)(t >> 5) * 32; c0 = (long)(t & 31) * 32;
  } else if (z < 11264) {               // w1: [1024][4096] -> [4096][1024]
    const int t = z - 7168;
    in = w1; out = W1T; ldin = 4096; ldout = 1024;
    r0 = (long)(t >> 7) * 32; c0 = (long)(t & 127) * 32;
  } else {                              // w2: [4096][1024] -> [1024][4096]
    const int t = z - 11264;
    in = w2; out = W2T; ldin = 1024; ldout = 4096;
    r0 = (long)(t >> 5) * 32; c0 = (long)(t & 31) * 32;
  }
  __shared__ unsigned short tile[32][33];
  const int tx = tid & 31, ty = tid >> 5;   // 32 x 8
#pragma unroll
  for (int i = 0; i < 4; i++)
    tile[ty + i * 8][tx] = f2bf(in[(r0 + ty + i * 8) * ldin + c0 + tx]);
  __syncthreads();
#pragma unroll
  for (int i = 0; i < 4; i++)
    out[(c0 + ty + i * 8) * ldout + r0 + tx] = tile[tx][ty + i * 8];
}

// ====== FFN GEMM: 256x128 tile, BK=32, 8 waves (4Mx2N), 2 blocks/CU ============
// Untested quadrant test: 256-row tile (known-good FETCH) at 2 blocks/CU
// (inter-block overlap masks barrier stalls; rounds 5-7 had 1/CU, round 8 had
// 4/CU but 128^2 tile with 3x refetch).  Per K-tile, minimal 2-barrier ledger:
//   {3 gloads (tile t+1 -> buf^1)} -> vmcnt(3)+bar (RAW: tile t landed, FIFO)
//   -> 6 ds_read_b128 -> lgkmcnt(0)+bar (WAR: reads drained before next-iter
//   overwrite) -> 16 MFMA.  Zero-conflict swizzle + coalesced repack epilogue.
template <bool RELU, bool PARTIAL>
__global__ __launch_bounds__(512, 2)
void gemm256n(const unsigned short* __restrict__ A, int lda,
              const unsigned short* __restrict__ B, int ldb,
              const float* __restrict__ bias,
              unsigned short* __restrict__ C,
              unsigned short* __restrict__ P1,
              unsigned short* __restrict__ P2,
              unsigned short* __restrict__ P3,
              int ldc, int nTN) {
  __shared__ unsigned short sm[32768];   // 64KB: A [2buf][256][32] @0..16384,
                                         // B [2buf][128][32] @16384..24576;
                                         // epilogue reuses as [256][128]
  const int tid = threadIdx.x;
  const int lane = tid & 63;
  const int wid = tid >> 6;
  const int wr = wid >> 1, wc = wid & 1;

  const unsigned int T = gridDim.x;
  const unsigned int q8 = T >> 3;
  const unsigned int x = blockIdx.x;
  const unsigned int swz = (x & 7) * q8 + (x >> 3);
  const long bm = (long)(swz / nTN) * 256;
  const long bn = (long)(swz % nTN) * 128;
  const long kbase = (long)blockIdx.y * 1024;

  f32x4 acc[4][4];
#pragma unroll
  for (int mf = 0; mf < 4; mf++)
#pragma unroll
    for (int nf = 0; nf < 4; nf++) acc[mf][nf] = f32x4{0.f, 0.f, 0.f, 0.f};

  const int strow = tid >> 2;                                  // 0..127
  const int scol = (((tid & 3) ^ ((tid >> 3) & 3)) << 3);      // pre-swizzled src
  const unsigned short* pA = A + (bm + strow) * lda + kbase + scol;
  const unsigned short* pB = B + (bn + strow) * ldb + kbase + scol;
  unsigned short* dA = sm + tid * 8;
  unsigned short* dB = sm + 16384 + tid * 8;

  const int g = lane >> 4;
  int offA[4], offB[4];
#pragma unroll
  for (int mf = 0; mf < 4; mf++) {
    const int rm = wr * 64 + mf * 16 + (lane & 15);            // 0..255
    offA[mf] = rm * 32 + ((g ^ ((rm >> 1) & 3)) << 3);
  }
#pragma unroll
  for (int nf = 0; nf < 4; nf++) {
    const int rb = wc * 64 + nf * 16 + (lane & 15);            // 0..127
    offB[nf] = rb * 32 + ((g ^ ((rb >> 1) & 3)) << 3);
  }

#define GA2(kt, rh, bu) gload16(pA + (long)(rh) * 128 * lda + (kt) * 32, \
                                dA + (bu) * 8192 + (rh) * 4096)
#define GB1(kt, bu)     gload16(pB + (kt) * 32, dB + (bu) * 4096)

  // prologue: tile 0 -> buf 0 (3 calls)
  GA2(0, 0, 0); GA2(0, 1, 0); GB1(0, 0);

  for (int t = 0; t < 32; ++t) {
    const int c = t & 1, n2 = c ^ 1;
    const int k1 = (t + 1) & 31;          // wrap: restaged, never read (safe)
    // issue tile t+1's stages into buf n2
    GA2(k1, 0, n2); GA2(k1, 1, n2); GB1(k1, n2);
    // RAW gate: tile t's 3 loads retired (the 3 newest stay in flight)
    asm volatile("s_waitcnt vmcnt(3)\ns_barrier" ::: "memory");

    const unsigned short* smA = sm + c * 8192;
    const unsigned short* smB = sm + 16384 + c * 4096;
    bf16x8 a_[4], b_[4];
#pragma unroll
    for (int nf = 0; nf < 4; nf++) b_[nf] = *(const bf16x8*)(smB + offB[nf]);
#pragma unroll
    for (int mf = 0; mf < 4; mf++) a_[mf] = *(const bf16x8*)(smA + offA[mf]);
    // WAR gate: all reads of buf c drained before next-iter gloads overwrite it
    asm volatile("s_waitcnt lgkmcnt(0)\ns_barrier" ::: "memory");
    __builtin_amdgcn_s_setprio(1);
#pragma unroll
    for (int mf = 0; mf < 4; mf++)
#pragma unroll
      for (int nf = 0; nf < 4; nf++)
        acc[mf][nf] = __builtin_amdgcn_mfma_f32_16x16x32_bf16(
            a_[mf], b_[nf], acc[mf][nf], 0, 0, 0);
    __builtin_amdgcn_s_setprio(0);
  }
#undef GA2
#undef GB1

  // drain wrap-stage gloads (target sm; also required before LDS reuse)
  asm volatile("s_waitcnt vmcnt(0)" ::: "memory");

  unsigned short* Cw = C;
  if (PARTIAL) {
    const int kc = blockIdx.y;
    Cw = (kc == 0) ? C : (kc == 1) ? P1 : (kc == 2) ? P2 : P3;
  }

  // ---- epilogue: repack [256][128] through LDS for full-line stores ----
  __syncthreads();
  {
    const int lrow = wr * 64 + ((lane >> 4) << 2);
    const int lcol = wc * 64 + (lane & 15);
#pragma unroll
    for (int nf = 0; nf < 4; nf++) {
      const int col = lcol + nf * 16;
      const float bv = PARTIAL ? 0.f : bias[bn + col];
#pragma unroll
      for (int mf = 0; mf < 4; mf++) {
#pragma unroll
        for (int i = 0; i < 4; i++) {
          float v = acc[mf][nf][i] + bv;
          if (RELU) v = fmaxf(v, 0.f);
          sm[(lrow + mf * 16 + i) * 128 + col] = f2bf(v);
        }
      }
    }
  }
  __syncthreads();
  const int srow = tid >> 4;             // 0..31
  const int scol8 = (tid & 15) * 8;      // 0..120
#pragma unroll
  for (int p = 0; p < 8; ++p) {
    const int r = p * 32 + srow;
    ushort8 vrow = *(const ushort8*)(sm + r * 128 + scol8);
    *(ushort8*)(&Cw[(bm + r) * ldc + bn + scol8]) = vrow;
  }
}

// ====== QKV GEMM: 128x384 tile -> 256 blocks; V fused into Vt ==================
__global__ __launch_bounds__(512, 2)
void gemm_qkv(const unsigned short* __restrict__ A,
              const unsigned short* __restrict__ B,
              const float* __restrict__ bias,
              unsigned short* __restrict__ C,
              unsigned short* __restrict__ Vt) {
  __shared__ unsigned short sm[65536];
  const int tid = threadIdx.x;
  const int lane = tid & 63;
  const int wid = tid >> 6;              // 0..7, owns 48 cols

  const unsigned int x = blockIdx.x;
  const unsigned int swz = (x & 7) * 32 + (x >> 3);
  const long bm = (long)(swz >> 3) * 128;
  const long bn = (long)(swz & 7) * 384;

  f32x4 acc[8][3];
#pragma unroll
  for (int mf = 0; mf < 8; mf++)
#pragma unroll
    for (int nf = 0; nf < 3; nf++) acc[mf][nf] = f32x4{0.f, 0.f, 0.f, 0.f};

  const int strow = tid >> 2;
  const int scol = (((tid & 3) ^ ((tid >> 3) & 3)) << 3);
  const unsigned short* pA = A + (bm + strow) * 1024 + scol;
  const unsigned short* pB = B + (bn + strow) * 1024 + scol;
  unsigned short* dA = sm + tid * 8;
  unsigned short* dB = sm + 16384 + tid * 8;

  const int g = lane >> 4;
  int offA[8], offB[3];
#pragma unroll
  for (int mf = 0; mf < 8; mf++) {
    const int rm = mf * 16 + (lane & 15);
    offA[mf] = rm * 32 + ((g ^ ((rm >> 1) & 3)) << 3);
  }
#pragma unroll
  for (int nf = 0; nf < 3; nf++) {
    const int rb = wid * 48 + nf * 16 + (lane & 15);
    offB[nf] = rb * 32 + ((g ^ ((rb >> 1) & 3)) << 3);
  }

#define GAQ(kt, ks, bu) gload16(pA + (kt) * 64 + (ks) * 32,                    \
                                dA + (bu) * 8192 + (ks) * 4096)
#define GBQ(kt, ks, rh, bu) gload16(pB + (long)(rh) * 128 * 1024 + (kt) * 64 + (ks) * 32, \
                                    dB + (bu) * 24576 + (ks) * 12288 + (rh) * 4096)
#define MFQ(AR, MO)                                                           \
  do {                                                                        \
    __builtin_amdgcn_s_setprio(1);                                            \
    _Pragma("unroll")                                                         \
    for (int mf = 0; mf < 4; mf++)                                            \
      _Pragma("unroll")                                                       \
      for (int nf = 0; nf < 3; nf++)                                          \
        acc[(MO) + mf][nf] = __builtin_amdgcn_mfma_f32_16x16x32_bf16(         \
            AR[mf], bcur[nf], acc[(MO) + mf][nf], 0, 0, 0);                   \
    __builtin_amdgcn_s_setprio(0);                                            \
  } while (0)

  GAQ(0, 0, 0); GAQ(0, 1, 0);
  GBQ(0, 0, 0, 0); GBQ(0, 0, 1, 0); GBQ(0, 0, 2, 0);
  GBQ(0, 1, 0, 0); GBQ(0, 1, 1, 0); GBQ(0, 1, 2, 0);

  for (int t = 0; t < 16; ++t) {
    const int c = t & 1, n2 = c ^ 1;
    const int k1 = t + 1;
    const unsigned short* smA = sm + c * 8192;
    const unsigned short* smB = sm + 16384 + c * 24576;
    bf16x8 a_[4], bcur[3];

    GAQ(k1, 0, n2); GAQ(k1, 1, n2);
    asm volatile("s_waitcnt vmcnt(2)\ns_barrier" ::: "memory");
#pragma unroll
    for (int nf = 0; nf < 3; nf++) bcur[nf] = *(const bf16x8*)(smB + offB[nf]);
#pragma unroll
    for (int mf = 0; mf < 4; mf++) a_[mf] = *(const bf16x8*)(smA + offA[mf]);
    MFQ(a_, 0);
    GBQ(k1, 0, 0, n2); GBQ(k1, 0, 1, n2);
#pragma unroll
    for (int mf = 0; mf < 4; mf++) a_[mf] = *(const bf16x8*)(smA + offA[4 + mf]);
    asm volatile("s_barrier" ::: "memory");
    MFQ(a_, 4);
    GBQ(k1, 0, 2, n2); GBQ(k1, 1, 0, n2);
#pragma unroll
    for (int nf = 0; nf < 3; nf++) bcur[nf] = *(const bf16x8*)(smB + 12288 + offB[nf]);
#pragma unroll
    for (int mf = 0; mf < 4; mf++) a_[mf] = *(const bf16x8*)(smA + 4096 + offA[mf]);
    asm volatile("s_barrier" ::: "memory");
    MFQ(a_, 0);
    GBQ(k1, 1, 1, n2); GBQ(k1, 1, 2, n2);
#pragma unroll
    for (int mf = 0; mf < 4; mf++) a_[mf] = *(const bf16x8*)(smA + 4096 + offA[4 + mf]);
    asm volatile("s_waitcnt lgkmcnt(0)\ns_barrier" ::: "memory");
    MFQ(a_, 4);
  }
#undef GAQ
#undef GBQ
#undef MFQ

  asm volatile("s_waitcnt vmcnt(0)" ::: "memory");

  const int bq16 = (int)(bm >> 9) * 16;
  const int s0 = (int)(bm & 511);
  const int lrow = (lane >> 4) << 2;
  const bool anyC = (bn < 2048);
  if (anyC) __syncthreads();

#pragma unroll
  for (int nf = 0; nf < 3; nf++) {
    const int gbase = (int)bn + wid * 48 + nf * 16;
    const float bv = bias[gbase + (lane & 15)];
    if (gbase >= 2048) {
      const int gc = gbase - 2048;
      const int h = gc >> 6;
      const int d = (gc & 63) + (lane & 15);
      unsigned short* vb = Vt + ((long)(bq16 + h) * 64 + d) * 512 + s0 + lrow;
#pragma unroll
      for (int mf = 0; mf < 8; mf++) {
        ushort4v o;
#pragma unroll
        for (int i = 0; i < 4; i++) o[i] = f2bf(acc[mf][nf][i] + bv);
        *(ushort4v*)(vb + mf * 16) = o;
      }
    } else {
      const int lc = wid * 48 + nf * 16 + (lane & 15);
#pragma unroll
      for (int mf = 0; mf < 8; mf++) {
#pragma unroll
        for (int i = 0; i < 4; i++)
          sm[(mf * 16 + lrow + i) * 384 + lc] = f2bf(acc[mf][nf][i] + bv);
      }
    }
  }

  if (anyC) {
    __syncthreads();
    const int r = tid >> 2;
    const int nseg = (bn == 1920) ? 4 : 12;
    for (int p = 0; p < nseg; ++p) {
      const int seg = p * 4 + (tid & 3);
      ushort8 v = *(const ushort8*)(sm + r * 384 + seg * 8);
      *(ushort8*)(&C[(bm + r) * 3072 + bn + seg * 8]) = v;
    }
  }
}

// =========== flash attention: 4 waves / 64 q-rows, XCD-grouped ==================
__global__ __launch_bounds__(256)
void attn_kernel(const unsigned short* __restrict__ QKV,
                 const unsigned short* __restrict__ Vt,
                 unsigned short* __restrict__ CTX) {
  const int lin = blockIdx.x;
  const int xcd = lin & 7;
  const int slot = lin >> 3;
  const int bh = xcd + 8 * (slot >> 3);
  const int qt = slot & 7;
  const int b = bh >> 4, h = bh & 15;
  const int tid = threadIdx.x;
  const int lane = tid & 63;
  const int wid = tid >> 6;

  __shared__ unsigned short Ks[64][72];
  __shared__ unsigned short Vs[64][72];
  __shared__ unsigned short Ps[4][16][72];

  const int qrow0 = qt * 64 + wid * 16;
  const unsigned short* Qb = QKV + (long)(b * SEQ + qrow0) * 3072 + h * 64;
  bf16x8 aq[2];
#pragma unroll
  for (int ks = 0; ks < 2; ks++)
    aq[ks] = *(const bf16x8*)(Qb + (long)(lane & 15) * 3072 + ks * 32 +
                              (lane >> 4) * 8);

  f32x4 acc_o[4];
#pragma unroll
  for (int n = 0; n < 4; n++) acc_o[n] = f32x4{0.f, 0.f, 0.f, 0.f};
  float rsum[4] = {0.f, 0.f, 0.f, 0.f};

  const int sr = tid >> 3;
  const int sc = (tid & 7) * 8;
  const unsigned short* Kg = QKV + (long)(b * SEQ) * 3072 + 1024 + h * 64 + sc;
  const unsigned short* Vg = Vt + (long)bh * (DK * SEQ) + sc;

  ushort8 kr0 = *(const ushort8*)(Kg + (long)sr * 3072);
  ushort8 kr1 = *(const ushort8*)(Kg + (long)(sr + 32) * 3072);
  ushort8 vr0 = *(const ushort8*)(Vg + (long)sr * SEQ);
  ushort8 vr1 = *(const ushort8*)(Vg + (long)(sr + 32) * SEQ);

#pragma unroll
  for (int c = 0; c < 8; ++c) {
    __syncthreads();
    *(ushort8*)(&Ks[sr][sc]) = kr0;
    *(ushort8*)(&Ks[sr + 32][sc]) = kr1;
    *(ushort8*)(&Vs[sr][sc]) = vr0;
    *(ushort8*)(&Vs[sr + 32][sc]) = vr1;
    if (c < 7) {
      kr0 = *(const ushort8*)(Kg + (long)((c + 1) * 64 + sr) * 3072);
      kr1 = *(const ushort8*)(Kg + (long)((c + 1) * 64 + sr + 32) * 3072);
      vr0 = *(const ushort8*)(Vg + (long)sr * SEQ + (c + 1) * 64);
      vr1 = *(const ushort8*)(Vg + (long)(sr + 32) * SEQ + (c + 1) * 64);
    }
    __syncthreads();

    f32x4 s[4];
#pragma unroll
    for (int n = 0; n < 4; n++) s[n] = f32x4{0.f, 0.f, 0.f, 0.f};
#pragma unroll
    for (int ks = 0; ks < 2; ks++) {
      bf16x8 kf[4];
#pragma unroll
      for (int n = 0; n < 4; n++)
        kf[n] = *(const bf16x8*)(&Ks[n * 16 + (lane & 15)][ks * 32 + (lane >> 4) * 8]);
#pragma unroll
      for (int n = 0; n < 4; n++)
        s[n] = __builtin_amdgcn_mfma_f32_16x16x32_bf16(aq[ks], kf[n], s[n], 0, 0, 0);
    }

#pragma unroll
    for (int n = 0; n < 4; n++) {
#pragma unroll
      for (int i = 0; i < 4; i++) {
        const float p = __expf(s[n][i] * 0.125f);
        rsum[i] += p;
        Ps[wid][(lane >> 4) * 4 + i][n * 16 + (lane & 15)] = f2bf(p);
      }
    }

#pragma unroll
    for (int ks = 0; ks < 2; ks++) {
      bf16x8 pa = *(const bf16x8*)(&Ps[wid][lane & 15][ks * 32 + (lane >> 4) * 8]);
      bf16x8 vf[4];
#pragma unroll
      for (int n = 0; n < 4; n++)
        vf[n] = *(const bf16x8*)(&Vs[n * 16 + (lane & 15)][ks * 32 + (lane >> 4) * 8]);
#pragma unroll
      for (int n = 0; n < 4; n++)
        acc_o[n] = __builtin_amdgcn_mfma_f32_16x16x32_bf16(pa, vf[n], acc_o[n], 0, 0, 0);
    }
  }

#pragma unroll
  for (int i = 0; i < 4; i++) {
#pragma unroll
    for (int off = 1; off < 16; off <<= 1) rsum[i] += __shfl_xor(rsum[i], off, 64);
  }

  const long orow0 = (long)(b * SEQ + qrow0);
#pragma unroll
  for (int i = 0; i < 4; i++) {
    const float inv = 1.f / rsum[i];
    const long r = orow0 + (lane >> 4) * 4 + i;
#pragma unroll
    for (int n = 0; n < 4; n++)
      CTX[r * DM + h * 64 + n * 16 + (lane & 15)] = f2bf(acc_o[n][i] * inv);
  }
}

// ---------------- LN1: LN(X(bf16) + R(bf16)) -> bf16 ----------------------------
__global__ __launch_bounds__(256)
void ln1_kernel(const unsigned short* __restrict__ X,
                const unsigned short* __restrict__ R,
                const float* __restrict__ g,
                const float* __restrict__ be,
                unsigned short* __restrict__ Ob) {
  const int t = blockIdx.x;
  const int tid = threadIdx.x;
  const long base = (long)t * DM + tid * 4;
  __shared__ float red[8];

  ushort4v xv = *(const ushort4v*)(X + base);
  ushort4v rv = *(const ushort4v*)(R + base);
  float v[4];
#pragma unroll
  for (int j = 0; j < 4; j++) v[j] = bf2f(xv[j]) + bf2f(rv[j]);
  float s = v[0] + v[1] + v[2] + v[3];
  float q = v[0] * v[0] + v[1] * v[1] + v[2] * v[2] + v[3] * v[3];
#pragma unroll
  for (int off = 1; off < 64; off <<= 1) {
    s += __shfl_xor(s, off, 64);
    q += __shfl_xor(q, off, 64);
  }
  if ((tid & 63) == 0) { red[tid >> 6] = s; red[4 + (tid >> 6)] = q; }
  __syncthreads();
  s = red[0] + red[1] + red[2] + red[3];
  q = red[4] + red[5] + red[6] + red[7];
  const float mu = s * (1.f / DM);
  const float var = q * (1.f / DM) - mu * mu;
  const float rstd = rsqrtf(fmaxf(var, 0.f) + 1e-5f);

  f32x4 gv = *(const f32x4*)(g + tid * 4);
  f32x4 bv = *(const f32x4*)(be + tid * 4);
  ushort4v ob;
#pragma unroll
  for (int j = 0; j < 4; j++)
    ob[j] = f2bf((v[j] - mu) * rstd * gv[j] + bv[j]);
  *(ushort4v*)(Ob + base) = ob;
}

// ---------------- LN2: LN(sum(4 bf16 partials) + b2 + X1(bf16)) -> f32 ----------
__global__ __launch_bounds__(256)
void ln2_kernel(const unsigned short* __restrict__ P0,
                const unsigned short* __restrict__ P1,
                const unsigned short* __restrict__ P2,
                const unsigned short* __restrict__ P3,
                const float* __restrict__ b2,
                const unsigned short* __restrict__ R,
                const float* __restrict__ g,
                const float* __restrict__ be,
                float* __restrict__ O) {
  const int t = blockIdx.x;
  const int tid = threadIdx.x;
  const long base = (long)t * DM + tid * 4;
  __shared__ float red[8];

  ushort4v p0 = *(const ushort4v*)(P0 + base);
  ushort4v p1 = *(const ushort4v*)(P1 + base);
  ushort4v p2 = *(const ushort4v*)(P2 + base);
  ushort4v p3 = *(const ushort4v*)(P3 + base);
  f32x4 bb = *(const f32x4*)(b2 + tid * 4);
  ushort4v rv = *(const ushort4v*)(R + base);
  float v[4];
#pragma unroll
  for (int j = 0; j < 4; j++)
    v[j] = bf2f(p0[j]) + bf2f(p1[j]) + bf2f(p2[j]) + bf2f(p3[j]) + bb[j] + bf2f(rv[j]);
  float s = v[0] + v[1] + v[2] + v[3];
  float q = v[0] * v[0] + v[1] * v[1] + v[2] * v[2] + v[3] * v[3];
#pragma unroll
  for (int off = 1; off < 64; off <<= 1) {
    s += __shfl_xor(s, off, 64);
    q += __shfl_xor(q, off, 64);
  }
  if ((tid & 63) == 0) { red[tid >> 6] = s; red[4 + (tid >> 6)] = q; }
  __syncthreads();
  s = red[0] + red[1] + red[2] + red[3];
  q = red[4] + red[5] + red[6] + red[7];
  const float mu = s * (1.f / DM);
  const float var = q * (1.f / DM) - mu * mu;
  const float rstd = rsqrtf(fmaxf(var, 0.f) + 1e-5f);

  f32x4 gv = *(const f32x4*)(g + tid * 4);
  f32x4 bv = *(const f32x4*)(be + tid * 4);
  f32x4 of;
#pragma unroll
  for (int j = 0; j < 4; j++) of[j] = (v[j] - mu) * rstd * gv[j] + bv[j];
  *(f32x4*)(O + base) = of;
}

// -------------------------------------------------------------------------------
extern "C" void kernel_launch(void* const* d_in, const int* in_sizes, int n_in,
                              void* d_out, int out_size, void* d_ws, size_t ws_size,
                              hipStream_t stream) {
  const float* src = (const float*)d_in[0];
  const float* wq  = (const float*)d_in[1];
  const float* bq  = (const float*)d_in[2];
  const float* wk  = (const float*)d_in[3];
  const float* bk  = (const float*)d_in[4];
  const float* wv  = (const float*)d_in[5];
  const float* bv  = (const float*)d_in[6];
  const float* g1  = (const float*)d_in[7];
  const float* be1 = (const float*)d_in[8];
  const float* w1  = (const float*)d_in[9];
  const float* b1  = (const float*)d_in[10];
  const float* w2  = (const float*)d_in[11];
  const float* b2  = (const float*)d_in[12];
  const float* g2  = (const float*)d_in[13];
  const float* be2 = (const float*)d_in[14];
  float* out = (float*)d_out;

  char* ws = (char*)d_ws;
  const size_t MB = 1024 * 1024;
  unsigned short* srcb  = (unsigned short*)(ws + 0);          //  8MB
  unsigned short* WqkvT = (unsigned short*)(ws + 8 * MB);     //  6MB
  float*          bqkv  = (float*)(ws + 14 * MB);             // 12KB
  unsigned short* W1T   = (unsigned short*)(ws + 15 * MB);    //  8MB
  unsigned short* W2T   = (unsigned short*)(ws + 23 * MB);    //  8MB
  unsigned short* QKV   = (unsigned short*)(ws + 31 * MB);    // 24MB (V third unused)
  unsigned short* Vtb   = (unsigned short*)(ws + 55 * MB);    //  8MB
  unsigned short* CTX   = (unsigned short*)(ws + 63 * MB);    //  8MB
  unsigned short* X1    = (unsigned short*)(ws + 71 * MB);    //  8MB (live to end)
  unsigned short* Pk3   = (unsigned short*)(ws + 79 * MB);    //  8MB -> 87MB
  // aliases of dead regions:
  unsigned short* Hb    = (unsigned short*)(ws + 31 * MB);    // 32MB (QKV+Vtb dead)
  unsigned short* Pk0   = (unsigned short*)(ws + 0);          //  8MB (srcb dead)
  unsigned short* Pk1   = (unsigned short*)(ws + 15 * MB);    //  8MB (W1T dead)
  unsigned short* Pk2   = (unsigned short*)(ws + 63 * MB);    //  8MB (CTX dead)
  if (ws_size < 87 * MB) return;

  // ONE prep launch: src convert + 5 transposes + bias concat
  prep_kernel<<<15372, 256, 0, stream>>>(src, srcb, wq, wk, wv, WqkvT,
                                         w1, W1T, w2, W2T, bq, bk, bv, bqkv);

  // QKV: 128x384 tiles -> 256 blocks; V fused into Vtb
  gemm_qkv<<<256, 512, 0, stream>>>(srcb, WqkvT, bqkv, QKV, Vtb);
  // attention: 1024 x 256-thr blocks, XCD-grouped per bh
  attn_kernel<<<1024, 256, 0, stream>>>(QKV, Vtb, CTX);
  // x = LN(ctx + src) -> bf16 only
  ln1_kernel<<<NTOK, 256, 0, stream>>>(CTX, srcb, g1, be1, X1);
  // h = relu(x @ w1 + b1) : 256x128 tiles -> 16x32 = 512 blocks (2/CU)
  gemm256n<true, false><<<dim3(512, 1), 512, 0, stream>>>(
      X1, 1024, W1T, 1024, b1, Hb, nullptr, nullptr, nullptr, 4096, 32);
  // y partials = h @ w2 (split-K 4x1024) : 16x8 = 128 tiles x 4 = 512 blocks
  gemm256n<false, true><<<dim3(128, 4), 512, 0, stream>>>(
      Hb, 4096, W2T, 4096, nullptr, Pk0, Pk1, Pk2, Pk3, 1024, 8);
  // out = LN(sum(partials) + b2 + x)
  ln2_kernel<<<NTOK, 256, 0, stream>>>(Pk0, Pk1, Pk2, Pk3, b2, X1, g2, be2, out);
}

// Round 17
// 159.615 us; speedup vs baseline: 1.0699x; 1.0699x over previous
//
#include <hip/hip_runtime.h>
#include <hip/hip_bf16.h>
#include <stdint.h>

#define DM   1024
#define FF   4096
#define NH   16
#define DK   64
#define SEQ  512
#define NTOK 4096

typedef __attribute__((ext_vector_type(8))) unsigned short ushort8;
typedef __attribute__((ext_vector_type(4))) unsigned short ushort4v;
typedef __attribute__((ext_vector_type(8))) short bf16x8;
typedef __attribute__((ext_vector_type(4))) float f32x4;

__device__ __forceinline__ float bf2f(unsigned short u) {
  union { unsigned int i; float f; } v; v.i = ((unsigned int)u) << 16; return v.f;
}
__device__ __forceinline__ unsigned short f2bf(float f) {
  union { float fl; unsigned int i; } v; v.fl = f;
  v.i += 0x7fffu + ((v.i >> 16) & 1u);   // RNE
  return (unsigned short)(v.i >> 16);
}

__device__ __forceinline__ void gload16(const unsigned short* g, unsigned short* l) {
  __builtin_amdgcn_global_load_lds(
      (const __attribute__((address_space(1))) unsigned int*)g,
      (__attribute__((address_space(3))) unsigned int*)l, 16, 0, 0);
}

// ============== mega-prep: src->bf16, 5 weight transposes, bias concat =========
__global__ __launch_bounds__(256)
void prep_kernel(const float* __restrict__ src, unsigned short* __restrict__ srcb,
                 const float* __restrict__ wq, const float* __restrict__ wk,
                 const float* __restrict__ wv, unsigned short* __restrict__ WqkvT,
                 const float* __restrict__ w1, unsigned short* __restrict__ W1T,
                 const float* __restrict__ w2, unsigned short* __restrict__ W2T,
                 const float* __restrict__ bq, const float* __restrict__ bk,
                 const float* __restrict__ bv, float* __restrict__ bqkv) {
  const int z = blockIdx.x;
  const int tid = threadIdx.x;
  if (z < 4096) {                       // src -> bf16 (1024 elems/block)
    const long i = ((long)z * 256 + tid) * 4;
    f32x4 v = *(const f32x4*)(src + i);
    ushort4v o;
#pragma unroll
    for (int j = 0; j < 4; j++) o[j] = f2bf(v[j]);
    *(ushort4v*)(srcb + i) = o;
    return;
  }
  if (z >= 15360) {                     // bias concat
    const int i = (z - 15360) * 256 + tid;
    if (i < 3072)
      bqkv[i] = (i < 1024) ? bq[i] : ((i < 2048) ? bk[i - 1024] : bv[i - 2048]);
    return;
  }
  // 32x32 transpose tile tasks
  const float* in;
  unsigned short* out;
  int ldin, ldout;
  long r0, c0;
  if (z < 7168) {                       // wq/wk/wv: [1024][1024]
    const int w = (z - 4096) >> 10;
    const int t = (z - 4096) & 1023;
    in = (w == 0) ? wq : (w == 1) ? wk : wv;
    out = WqkvT + (long)w * 1024 * 1024;
    ldin = 1024; ldout = 1024;
    r0 = (long)(t >> 5) * 32; c0 = (long)(t & 31) * 32;
  } else if (z < 11264) {               // w1: [1024][4096] -> [4096][1024]
    const int t = z - 7168;
    in = w1; out = W1T; ldin = 4096; ldout = 1024;
    r0 = (long)(t >> 7) * 32; c0 = (long)(t & 127) * 32;
  } else {                              // w2: [4096][1024] -> [1024][4096]
    const int t = z - 11264;
    in = w2; out = W2T; ldin = 1024; ldout = 4096;
    r0 = (long)(t >> 5) * 32; c0 = (long)(t & 31) * 32;
  }
  __shared__ unsigned short tile[32][33];
  const int tx = tid & 31, ty = tid >> 5;   // 32 x 8
#pragma unroll
  for (int i = 0; i < 4; i++)
    tile[ty + i * 8][tx] = f2bf(in[(r0 + ty + i * 8) * ldin + c0 + tx]);
  __syncthreads();
#pragma unroll
  for (int i = 0; i < 4; i++)
    out[(c0 + ty + i * 8) * ldout + r0 + tx] = tile[tx][ty + i * 8];
}

// ====== 256x256 BK=64 4-phase GEMM + coalesced C-write (FFN1/FFN2) =============
template <bool RELU, bool PARTIAL>
__global__ __launch_bounds__(512, 2)
void gemm256(const unsigned short* __restrict__ A, int lda,
             const unsigned short* __restrict__ B, int ldb,
             const float* __restrict__ bias,
             unsigned short* __restrict__ C,
             unsigned short* __restrict__ P1,
             unsigned short* __restrict__ P2,
             unsigned short* __restrict__ P3,
             int ldc, int nTN) {
  __shared__ unsigned short sm[65536];
  const int tid = threadIdx.x;
  const int lane = tid & 63;
  const int wid = tid >> 6;
  const int wr = wid >> 2, wc = wid & 3;
  const int kgrp = wid >> 2;

  const unsigned int T = gridDim.x;
  const unsigned int q8 = T >> 3;
  const unsigned int x = blockIdx.x;
  const unsigned int swz = (x & 7) * q8 + (x >> 3);
  const long bm = (long)(swz / nTN) * 256;
  const long bn = (long)(swz % nTN) * 256;
  const long kbase = (long)blockIdx.y * 1024;

  f32x4 acc[8][4];
#pragma unroll
  for (int mf = 0; mf < 8; mf++)
#pragma unroll
    for (int nf = 0; nf < 4; nf++) acc[mf][nf] = f32x4{0.f, 0.f, 0.f, 0.f};

  const int strow = tid >> 2;
  const int scol = (((tid & 3) ^ ((tid >> 3) & 3)) << 3);
  const unsigned short* pA = A + (bm + strow) * lda + kbase + scol;
  const unsigned short* pB = B + (bn + strow) * ldb + kbase + scol;
  unsigned short* dA = sm + tid * 8;
  unsigned short* dB = sm + 32768 + tid * 8;

  const int g = lane >> 4;
  int offA[8], offB[4];
#pragma unroll
  for (int mf = 0; mf < 8; mf++) {
    const int rm = wr * 128 + mf * 16 + (lane & 15);
    offA[mf] = rm * 32 + ((g ^ ((rm >> 1) & 3)) << 3);
  }
#pragma unroll
  for (int nf = 0; nf < 4; nf++) {
    const int rb = wc * 64 + nf * 16 + (lane & 15);
    offB[nf] = rb * 32 + ((g ^ ((rb >> 1) & 3)) << 3);
  }

#define GA(kt, ks, rh, bu) gload16(pA + (long)(rh) * 128 * lda + (kt) * 64 + (ks) * 32, \
                                   dA + (bu) * 16384 + (ks) * 8192 + (rh) * 4096)
#define GB(kt, ks, rh, bu) gload16(pB + (long)(rh) * 128 * ldb + (kt) * 64 + (ks) * 32, \
                                   dB + (bu) * 16384 + (ks) * 8192 + (rh) * 4096)
#define MF16(AR, BR, MO)                                                      \
  do {                                                                        \
    __builtin_amdgcn_s_setprio(1);                                            \
    _Pragma("unroll")                                                         \
    for (int mf = 0; mf < 4; mf++)                                            \
      _Pragma("unroll")                                                       \
      for (int nf = 0; nf < 4; nf++)                                          \
        acc[(MO) + mf][nf] = __builtin_amdgcn_mfma_f32_16x16x32_bf16(         \
            AR[mf], BR[nf], acc[(MO) + mf][nf], 0, 0, 0);                     \
    __builtin_amdgcn_s_setprio(0);                                            \
  } while (0)

  GA(0, 0, 0, 0); GA(0, 0, 1, 0); GA(0, 1, 0, 0); GA(0, 1, 1, 0);
  GB(0, 0, 0, 0); GB(0, 0, 1, 0); GB(0, 1, 0, 0); GB(0, 1, 1, 0);

  for (int t = 0; t < 16; ++t) {
    const int c = t & 1, n2 = c ^ 1;
    const int k1 = t + 1;                 // t=15 stages garbage (valid ws, unread)
    const unsigned short* smAc = sm + c * 16384;
    const unsigned short* smBc = sm + 32768 + c * 16384;
    bf16x8 a_[4], bcur[4];
    const int ks0off = kgrp * 8192;
    const int ks1off = (1 - kgrp) * 8192;

    GA(k1, 0, 0, n2); GA(k1, 0, 1, n2);
    asm volatile("s_waitcnt vmcnt(2)\ns_barrier" ::: "memory");
#pragma unroll
    for (int nf = 0; nf < 4; nf++) bcur[nf] = *(const bf16x8*)(smBc + ks0off + offB[nf]);
#pragma unroll
    for (int mf = 0; mf < 4; mf++) a_[mf] = *(const bf16x8*)(smAc + ks0off + offA[mf]);
    MF16(a_, bcur, 0);
    GA(k1, 1, 0, n2); GA(k1, 1, 1, n2);
#pragma unroll
    for (int mf = 0; mf < 4; mf++) a_[mf] = *(const bf16x8*)(smAc + ks0off + offA[4 + mf]);
    asm volatile("s_barrier" ::: "memory");
    MF16(a_, bcur, 4);
    GB(k1, 0, 0, n2); GB(k1, 0, 1, n2);
#pragma unroll
    for (int nf = 0; nf < 4; nf++) bcur[nf] = *(const bf16x8*)(smBc + ks1off + offB[nf]);
#pragma unroll
    for (int mf = 0; mf < 4; mf++) a_[mf] = *(const bf16x8*)(smAc + ks1off + offA[mf]);
    asm volatile("s_barrier" ::: "memory");
    MF16(a_, bcur, 0);
    GB(k1, 1, 0, n2); GB(k1, 1, 1, n2);
#pragma unroll
    for (int mf = 0; mf < 4; mf++) a_[mf] = *(const bf16x8*)(smAc + ks1off + offA[4 + mf]);
    asm volatile("s_waitcnt lgkmcnt(0)\ns_barrier" ::: "memory");
    MF16(a_, bcur, 4);
  }
#undef GA
#undef GB
#undef MF16

  asm volatile("s_waitcnt vmcnt(0)" ::: "memory");

  unsigned short* Cw = C;
  if (PARTIAL) {
    const int kc = blockIdx.y;
    Cw = (kc == 0) ? C : (kc == 1) ? P1 : (kc == 2) ? P2 : P3;
  }

  __syncthreads();
  {
    const int lrow = wr * 128 + ((lane >> 4) << 2);
    const int lcol = wc * 64 + (lane & 15);
#pragma unroll
    for (int nf = 0; nf < 4; nf++) {
      const int col = lcol + nf * 16;
      const float bv = PARTIAL ? 0.f : bias[bn + col];
#pragma unroll
      for (int mf = 0; mf < 8; mf++) {
#pragma unroll
        for (int i = 0; i < 4; i++) {
          float v = acc[mf][nf][i] + bv;
          if (RELU) v = fmaxf(v, 0.f);
          sm[(lrow + mf * 16 + i) * 256 + col] = f2bf(v);
        }
      }
    }
  }
  __syncthreads();
  const int srow = tid >> 5;
  const int scol8 = (tid & 31) * 8;
#pragma unroll
  for (int p = 0; p < 16; ++p) {
    const int r = p * 16 + srow;
    ushort8 vrow = *(const ushort8*)(sm + r * 256 + scol8);
    *(ushort8*)(&Cw[(bm + r) * ldc + bn + scol8]) = vrow;
  }
}

// ====== QKV GEMM: 128x384 tile -> 256 blocks; V fused into Vt ==================
__global__ __launch_bounds__(512, 2)
void gemm_qkv(const unsigned short* __restrict__ A,
              const unsigned short* __restrict__ B,
              const float* __restrict__ bias,
              unsigned short* __restrict__ C,
              unsigned short* __restrict__ Vt) {
  __shared__ unsigned short sm[65536];
  const int tid = threadIdx.x;
  const int lane = tid & 63;
  const int wid = tid >> 6;              // 0..7, owns 48 cols

  const unsigned int x = blockIdx.x;
  const unsigned int swz = (x & 7) * 32 + (x >> 3);
  const long bm = (long)(swz >> 3) * 128;
  const long bn = (long)(swz & 7) * 384;

  f32x4 acc[8][3];
#pragma unroll
  for (int mf = 0; mf < 8; mf++)
#pragma unroll
    for (int nf = 0; nf < 3; nf++) acc[mf][nf] = f32x4{0.f, 0.f, 0.f, 0.f};

  const int strow = tid >> 2;
  const int scol = (((tid & 3) ^ ((tid >> 3) & 3)) << 3);
  const unsigned short* pA = A + (bm + strow) * 1024 + scol;
  const unsigned short* pB = B + (bn + strow) * 1024 + scol;
  unsigned short* dA = sm + tid * 8;
  unsigned short* dB = sm + 16384 + tid * 8;

  const int g = lane >> 4;
  int offA[8], offB[3];
#pragma unroll
  for (int mf = 0; mf < 8; mf++) {
    const int rm = mf * 16 + (lane & 15);
    offA[mf] = rm * 32 + ((g ^ ((rm >> 1) & 3)) << 3);
  }
#pragma unroll
  for (int nf = 0; nf < 3; nf++) {
    const int rb = wid * 48 + nf * 16 + (lane & 15);
    offB[nf] = rb * 32 + ((g ^ ((rb >> 1) & 3)) << 3);
  }

#define GAQ(kt, ks, bu) gload16(pA + (kt) * 64 + (ks) * 32,                    \
                                dA + (bu) * 8192 + (ks) * 4096)
#define GBQ(kt, ks, rh, bu) gload16(pB + (long)(rh) * 128 * 1024 + (kt) * 64 + (ks) * 32, \
                                    dB + (bu) * 24576 + (ks) * 12288 + (rh) * 4096)
#define MFQ(AR, MO)                                                           \
  do {                                                                        \
    __builtin_amdgcn_s_setprio(1);                                            \
    _Pragma("unroll")                                                         \
    for (int mf = 0; mf < 4; mf++)                                            \
      _Pragma("unroll")                                                       \
      for (int nf = 0; nf < 3; nf++)                                          \
        acc[(MO) + mf][nf] = __builtin_amdgcn_mfma_f32_16x16x32_bf16(         \
            AR[mf], bcur[nf], acc[(MO) + mf][nf], 0, 0, 0);                   \
    __builtin_amdgcn_s_setprio(0);                                            \
  } while (0)

  GAQ(0, 0, 0); GAQ(0, 1, 0);
  GBQ(0, 0, 0, 0); GBQ(0, 0, 1, 0); GBQ(0, 0, 2, 0);
  GBQ(0, 1, 0, 0); GBQ(0, 1, 1, 0); GBQ(0, 1, 2, 0);

  for (int t = 0; t < 16; ++t) {
    const int c = t & 1, n2 = c ^ 1;
    const int k1 = t + 1;
    const unsigned short* smA = sm + c * 8192;
    const unsigned short* smB = sm + 16384 + c * 24576;
    bf16x8 a_[4], bcur[3];

    GAQ(k1, 0, n2); GAQ(k1, 1, n2);
    asm volatile("s_waitcnt vmcnt(2)\ns_barrier" ::: "memory");
#pragma unroll
    for (int nf = 0; nf < 3; nf++) bcur[nf] = *(const bf16x8*)(smB + offB[nf]);
#pragma unroll
    for (int mf = 0; mf < 4; mf++) a_[mf] = *(const bf16x8*)(smA + offA[mf]);
    MFQ(a_, 0);
    GBQ(k1, 0, 0, n2); GBQ(k1, 0, 1, n2);
#pragma unroll
    for (int mf = 0; mf < 4; mf++) a_[mf] = *(const bf16x8*)(smA + offA[4 + mf]);
    asm volatile("s_barrier" ::: "memory");
    MFQ(a_, 4);
    GBQ(k1, 0, 2, n2); GBQ(k1, 1, 0, n2);
#pragma unroll
    for (int nf = 0; nf < 3; nf++) bcur[nf] = *(const bf16x8*)(smB + 12288 + offB[nf]);
#pragma unroll
    for (int mf = 0; mf < 4; mf++) a_[mf] = *(const bf16x8*)(smA + 4096 + offA[mf]);
    asm volatile("s_barrier" ::: "memory");
    MFQ(a_, 0);
    GBQ(k1, 1, 1, n2); GBQ(k1, 1, 2, n2);
#pragma unroll
    for (int mf = 0; mf < 4; mf++) a_[mf] = *(const bf16x8*)(smA + 4096 + offA[4 + mf]);
    asm volatile("s_waitcnt lgkmcnt(0)\ns_barrier" ::: "memory");
    MFQ(a_, 4);
  }
#undef GAQ
#undef GBQ
#undef MFQ

  asm volatile("s_waitcnt vmcnt(0)" ::: "memory");

  const int bq16 = (int)(bm >> 9) * 16;
  const int s0 = (int)(bm & 511);
  const int lrow = (lane >> 4) << 2;
  const bool anyC = (bn < 2048);
  if (anyC) __syncthreads();

#pragma unroll
  for (int nf = 0; nf < 3; nf++) {
    const int gbase = (int)bn + wid * 48 + nf * 16;
    const float bv = bias[gbase + (lane & 15)];
    if (gbase >= 2048) {
      const int gc = gbase - 2048;
      const int h = gc >> 6;
      const int d = (gc & 63) + (lane & 15);
      unsigned short* vb = Vt + ((long)(bq16 + h) * 64 + d) * 512 + s0 + lrow;
#pragma unroll
      for (int mf = 0; mf < 8; mf++) {
        ushort4v o;
#pragma unroll
        for (int i = 0; i < 4; i++) o[i] = f2bf(acc[mf][nf][i] + bv);
        *(ushort4v*)(vb + mf * 16) = o;
      }
    } else {
      const int lc = wid * 48 + nf * 16 + (lane & 15);
#pragma unroll
      for (int mf = 0; mf < 8; mf++) {
#pragma unroll
        for (int i = 0; i < 4; i++)
          sm[(mf * 16 + lrow + i) * 384 + lc] = f2bf(acc[mf][nf][i] + bv);
      }
    }
  }

  if (anyC) {
    __syncthreads();
    const int r = tid >> 2;
    const int nseg = (bn == 1920) ? 4 : 12;
    for (int p = 0; p < nseg; ++p) {
      const int seg = p * 4 + (tid & 3);
      ushort8 v = *(const ushort8*)(sm + r * 384 + seg * 8);
      *(ushort8*)(&C[(bm + r) * 3072 + bn + seg * 8]) = v;
    }
  }
}

// =========== flash attention: 4 waves / 64 q-rows, XCD-grouped ==================
__global__ __launch_bounds__(256)
void attn_kernel(const unsigned short* __restrict__ QKV,
                 const unsigned short* __restrict__ Vt,
                 unsigned short* __restrict__ CTX) {
  const int lin = blockIdx.x;
  const int xcd = lin & 7;
  const int slot = lin >> 3;
  const int bh = xcd + 8 * (slot >> 3);
  const int qt = slot & 7;
  const int b = bh >> 4, h = bh & 15;
  const int tid = threadIdx.x;
  const int lane = tid & 63;
  const int wid = tid >> 6;

  __shared__ unsigned short Ks[64][72];
  __shared__ unsigned short Vs[64][72];
  __shared__ unsigned short Ps[4][16][72];

  const int qrow0 = qt * 64 + wid * 16;
  const unsigned short* Qb = QKV + (long)(b * SEQ + qrow0) * 3072 + h * 64;
  bf16x8 aq[2];
#pragma unroll
  for (int ks = 0; ks < 2; ks++)
    aq[ks] = *(const bf16x8*)(Qb + (long)(lane & 15) * 3072 + ks * 32 +
                              (lane >> 4) * 8);

  f32x4 acc_o[4];
#pragma unroll
  for (int n = 0; n < 4; n++) acc_o[n] = f32x4{0.f, 0.f, 0.f, 0.f};
  float rsum[4] = {0.f, 0.f, 0.f, 0.f};

  const int sr = tid >> 3;
  const int sc = (tid & 7) * 8;
  const unsigned short* Kg = QKV + (long)(b * SEQ) * 3072 + 1024 + h * 64 + sc;
  const unsigned short* Vg = Vt + (long)bh * (DK * SEQ) + sc;

  ushort8 kr0 = *(const ushort8*)(Kg + (long)sr * 3072);
  ushort8 kr1 = *(const ushort8*)(Kg + (long)(sr + 32) * 3072);
  ushort8 vr0 = *(const ushort8*)(Vg + (long)sr * SEQ);
  ushort8 vr1 = *(const ushort8*)(Vg + (long)(sr + 32) * SEQ);

#pragma unroll
  for (int c = 0; c < 8; ++c) {
    __syncthreads();
    *(ushort8*)(&Ks[sr][sc]) = kr0;
    *(ushort8*)(&Ks[sr + 32][sc]) = kr1;
    *(ushort8*)(&Vs[sr][sc]) = vr0;
    *(ushort8*)(&Vs[sr + 32][sc]) = vr1;
    if (c < 7) {
      kr0 = *(const ushort8*)(Kg + (long)((c + 1) * 64 + sr) * 3072);
      kr1 = *(const ushort8*)(Kg + (long)((c + 1) * 64 + sr + 32) * 3072);
      vr0 = *(const ushort8*)(Vg + (long)sr * SEQ + (c + 1) * 64);
      vr1 = *(const ushort8*)(Vg + (long)(sr + 32) * SEQ + (c + 1) * 64);
    }
    __syncthreads();

    f32x4 s[4];
#pragma unroll
    for (int n = 0; n < 4; n++) s[n] = f32x4{0.f, 0.f, 0.f, 0.f};
#pragma unroll
    for (int ks = 0; ks < 2; ks++) {
      bf16x8 kf[4];
#pragma unroll
      for (int n = 0; n < 4; n++)
        kf[n] = *(const bf16x8*)(&Ks[n * 16 + (lane & 15)][ks * 32 + (lane >> 4) * 8]);
#pragma unroll
      for (int n = 0; n < 4; n++)
        s[n] = __builtin_amdgcn_mfma_f32_16x16x32_bf16(aq[ks], kf[n], s[n], 0, 0, 0);
    }

#pragma unroll
    for (int n = 0; n < 4; n++) {
#pragma unroll
      for (int i = 0; i < 4; i++) {
        const float p = __expf(s[n][i] * 0.125f);
        rsum[i] += p;
        Ps[wid][(lane >> 4) * 4 + i][n * 16 + (lane & 15)] = f2bf(p);
      }
    }

#pragma unroll
    for (int ks = 0; ks < 2; ks++) {
      bf16x8 pa = *(const bf16x8*)(&Ps[wid][lane & 15][ks * 32 + (lane >> 4) * 8]);
      bf16x8 vf[4];
#pragma unroll
      for (int n = 0; n < 4; n++)
        vf[n] = *(const bf16x8*)(&Vs[n * 16 + (lane & 15)][ks * 32 + (lane >> 4) * 8]);
#pragma unroll
      for (int n = 0; n < 4; n++)
        acc_o[n] = __builtin_amdgcn_mfma_f32_16x16x32_bf16(pa, vf[n], acc_o[n], 0, 0, 0);
    }
  }

#pragma unroll
  for (int i = 0; i < 4; i++) {
#pragma unroll
    for (int off = 1; off < 16; off <<= 1) rsum[i] += __shfl_xor(rsum[i], off, 64);
  }

  const long orow0 = (long)(b * SEQ + qrow0);
#pragma unroll
  for (int i = 0; i < 4; i++) {
    const float inv = 1.f / rsum[i];
    const long r = orow0 + (lane >> 4) * 4 + i;
#pragma unroll
    for (int n = 0; n < 4; n++)
      CTX[r * DM + h * 64 + n * 16 + (lane & 15)] = f2bf(acc_o[n][i] * inv);
  }
}

// ---------------- LN1: LN(X(bf16) + R(bf16)) -> bf16 ----------------------------
__global__ __launch_bounds__(256)
void ln1_kernel(const unsigned short* __restrict__ X,
                const unsigned short* __restrict__ R,
                const float* __restrict__ g,
                const float* __restrict__ be,
                unsigned short* __restrict__ Ob) {
  const int t = blockIdx.x;
  const int tid = threadIdx.x;
  const long base = (long)t * DM + tid * 4;
  __shared__ float red[8];

  ushort4v xv = *(const ushort4v*)(X + base);
  ushort4v rv = *(const ushort4v*)(R + base);
  float v[4];
#pragma unroll
  for (int j = 0; j < 4; j++) v[j] = bf2f(xv[j]) + bf2f(rv[j]);
  float s = v[0] + v[1] + v[2] + v[3];
  float q = v[0] * v[0] + v[1] * v[1] + v[2] * v[2] + v[3] * v[3];
#pragma unroll
  for (int off = 1; off < 64; off <<= 1) {
    s += __shfl_xor(s, off, 64);
    q += __shfl_xor(q, off, 64);
  }
  if ((tid & 63) == 0) { red[tid >> 6] = s; red[4 + (tid >> 6)] = q; }
  __syncthreads();
  s = red[0] + red[1] + red[2] + red[3];
  q = red[4] + red[5] + red[6] + red[7];
  const float mu = s * (1.f / DM);
  const float var = q * (1.f / DM) - mu * mu;
  const float rstd = rsqrtf(fmaxf(var, 0.f) + 1e-5f);

  f32x4 gv = *(const f32x4*)(g + tid * 4);
  f32x4 bv = *(const f32x4*)(be + tid * 4);
  ushort4v ob;
#pragma unroll
  for (int j = 0; j < 4; j++)
    ob[j] = f2bf((v[j] - mu) * rstd * gv[j] + bv[j]);
  *(ushort4v*)(Ob + base) = ob;
}

// ---------------- LN2: LN(sum(4 bf16 partials) + b2 + X1(bf16)) -> f32 ----------
__global__ __launch_bounds__(256)
void ln2_kernel(const unsigned short* __restrict__ P0,
                const unsigned short* __restrict__ P1,
                const unsigned short* __restrict__ P2,
                const unsigned short* __restrict__ P3,
                const float* __restrict__ b2,
                const unsigned short* __restrict__ R,
                const float* __restrict__ g,
                const float* __restrict__ be,
                float* __restrict__ O) {
  const int t = blockIdx.x;
  const int tid = threadIdx.x;
  const long base = (long)t * DM + tid * 4;
  __shared__ float red[8];

  ushort4v p0 = *(const ushort4v*)(P0 + base);
  ushort4v p1 = *(const ushort4v*)(P1 + base);
  ushort4v p2 = *(const ushort4v*)(P2 + base);
  ushort4v p3 = *(const ushort4v*)(P3 + base);
  f32x4 bb = *(const f32x4*)(b2 + tid * 4);
  ushort4v rv = *(const ushort4v*)(R + base);
  float v[4];
#pragma unroll
  for (int j = 0; j < 4; j++)
    v[j] = bf2f(p0[j]) + bf2f(p1[j]) + bf2f(p2[j]) + bf2f(p3[j]) + bb[j] + bf2f(rv[j]);
  float s = v[0] + v[1] + v[2] + v[3];
  float q = v[0] * v[0] + v[1] * v[1] + v[2] * v[2] + v[3] * v[3];
#pragma unroll
  for (int off = 1; off < 64; off <<= 1) {
    s += __shfl_xor(s, off, 64);
    q += __shfl_xor(q, off, 64);
  }
  if ((tid & 63) == 0) { red[tid >> 6] = s; red[4 + (tid >> 6)] = q; }
  __syncthreads();
  s = red[0] + red[1] + red[2] + red[3];
  q = red[4] + red[5] + red[6] + red[7];
  const float mu = s * (1.f / DM);
  const float var = q * (1.f / DM) - mu * mu;
  const float rstd = rsqrtf(fmaxf(var, 0.f) + 1e-5f);

  f32x4 gv = *(const f32x4*)(g + tid * 4);
  f32x4 bv = *(const f32x4*)(be + tid * 4);
  f32x4 of;
#pragma unroll
  for (int j = 0; j < 4; j++) of[j] = (v[j] - mu) * rstd * gv[j] + bv[j];
  *(f32x4*)(O + base) = of;
}

// -------------------------------------------------------------------------------
extern "C" void kernel_launch(void* const* d_in, const int* in_sizes, int n_in,
                              void* d_out, int out_size, void* d_ws, size_t ws_size,
                              hipStream_t stream) {
  const float* src = (const float*)d_in[0];
  const float* wq  = (const float*)d_in[1];
  const float* bq  = (const float*)d_in[2];
  const float* wk  = (const float*)d_in[3];
  const float* bk  = (const float*)d_in[4];
  const float* wv  = (const float*)d_in[5];
  const float* bv  = (const float*)d_in[6];
  const float* g1  = (const float*)d_in[7];
  const float* be1 = (const float*)d_in[8];
  const float* w1  = (const float*)d_in[9];
  const float* b1  = (const float*)d_in[10];
  const float* w2  = (const float*)d_in[11];
  const float* b2  = (const float*)d_in[12];
  const float* g2  = (const float*)d_in[13];
  const float* be2 = (const float*)d_in[14];
  float* out = (float*)d_out;

  char* ws = (char*)d_ws;
  const size_t MB = 1024 * 1024;
  unsigned short* srcb  = (unsigned short*)(ws + 0);          //  8MB
  unsigned short* WqkvT = (unsigned short*)(ws + 8 * MB);     //  6MB
  float*          bqkv  = (float*)(ws + 14 * MB);             // 12KB
  unsigned short* W1T   = (unsigned short*)(ws + 15 * MB);    //  8MB
  unsigned short* W2T   = (unsigned short*)(ws + 23 * MB);    //  8MB
  unsigned short* QKV   = (unsigned short*)(ws + 31 * MB);    // 24MB (V third unused)
  unsigned short* Vtb   = (unsigned short*)(ws + 55 * MB);    //  8MB
  unsigned short* CTX   = (unsigned short*)(ws + 63 * MB);    //  8MB
  unsigned short* X1    = (unsigned short*)(ws + 71 * MB);    //  8MB (live to end)
  unsigned short* Pk3   = (unsigned short*)(ws + 79 * MB);    //  8MB -> 87MB
  // aliases of dead regions:
  unsigned short* Hb    = (unsigned short*)(ws + 31 * MB);    // 32MB (QKV+Vtb dead)
  unsigned short* Pk0   = (unsigned short*)(ws + 0);          //  8MB (srcb dead)
  unsigned short* Pk1   = (unsigned short*)(ws + 15 * MB);    //  8MB (W1T dead)
  unsigned short* Pk2   = (unsigned short*)(ws + 63 * MB);    //  8MB (CTX dead)
  if (ws_size < 87 * MB) return;

  // ONE prep launch: src convert + 5 transposes + bias concat
  prep_kernel<<<15372, 256, 0, stream>>>(src, srcb, wq, wk, wv, WqkvT,
                                         w1, W1T, w2, W2T, bq, bk, bv, bqkv);

  // QKV: 128x384 tiles -> 256 blocks; V fused into Vtb
  gemm_qkv<<<256, 512, 0, stream>>>(srcb, WqkvT, bqkv, QKV, Vtb);
  // attention: 1024 x 256-thr blocks, XCD-grouped per bh
  attn_kernel<<<1024, 256, 0, stream>>>(QKV, Vtb, CTX);
  // x = LN(ctx + src) -> bf16 only
  ln1_kernel<<<NTOK, 256, 0, stream>>>(CTX, srcb, g1, be1, X1);
  // h = relu(x @ w1 + b1) : M=4096, N=4096, K=1024 -> 256 tiles
  gemm256<true, false><<<dim3(256, 1), 512, 0, stream>>>(
      X1, 1024, W1T, 1024, b1, Hb, nullptr, nullptr, nullptr, 4096, 16);
  // y partials = h @ w2 (split-K 4x1024) : M=4096, N=1024 -> 64 tiles x 4
  gemm256<false, true><<<dim3(64, 4), 512, 0, stream>>>(
      Hb, 4096, W2T, 4096, nullptr, Pk0, Pk1, Pk2, Pk3, 1024, 4);
  // out = LN(sum(partials) + b2 + x)
  ln2_kernel<<<NTOK, 256, 0, stream>>>(Pk0, Pk1, Pk2, Pk3, b2, X1, g2, be2, out);
}